// Round 1
// baseline (407.732 us; speedup 1.0000x reference)
//
#include <hip/hip_runtime.h>
#include <hip/hip_bf16.h>
#include <math.h>

#define HIDDEN 128
#define EPS_G 1e-8f

// ---------------------------------------------------------------------------
// Kernel 0: PetB[t][c] = b1[c] + sum_{k<16} etype_emb[t][k] * W1[256+k][c]
// ---------------------------------------------------------------------------
__global__ __launch_bounds__(256) void etype_proj_kernel(
    const float* __restrict__ ee, const float* __restrict__ W1,
    const float* __restrict__ b1, float* __restrict__ PetB, int n_etypes)
{
    int gid = blockIdx.x * 256 + threadIdx.x;
    int t = gid >> 7;          // /128
    int c = gid & 127;
    if (t >= n_etypes) return;
    float acc = b1[c];
    #pragma unroll
    for (int k = 0; k < 16; ++k) {
        acc = fmaf(ee[t * 16 + k], W1[(256 + k) * 128 + c], acc);
    }
    PetB[t * 128 + c] = acc;
}

// ---------------------------------------------------------------------------
// Kernel 1: P[m][0:128]   = x[m] @ W1[0:128]     (src half)
//           P[m][128:256] = x[m] @ W1[128:256]   (dst half)
// Tiled fp32 GEMM: BM=64, BN=128 (blockIdx.y picks half), BK=32.
// ---------------------------------------------------------------------------
#define BM 64
#define BK 32
#define BN 128
#define APAD 36   // row stride in floats: 144B, 16B-aligned, breaks bank repeat

__global__ __launch_bounds__(256) void node_proj_kernel(
    const float* __restrict__ x, const float* __restrict__ W1,
    float* __restrict__ P, int n_nodes)
{
    __shared__ float As[BM * APAD];      // 64 x 36 floats = 9216 B
    __shared__ float Bs[BK * BN];        // 32 x 128 floats = 16384 B

    const int tid  = threadIdx.x;
    const int m0   = blockIdx.x * BM;
    const int half = blockIdx.y;         // 0: src cols, 1: dst cols
    const int tm   = tid >> 5;           // 0..7  -> rows tm*8 .. tm*8+7
    const int tn   = tid & 31;           // 0..31 -> cols tn*4 .. tn*4+3

    float acc[8][4];
    #pragma unroll
    for (int i = 0; i < 8; ++i)
        #pragma unroll
        for (int j = 0; j < 4; ++j) acc[i][j] = 0.f;

    const float* Wbase = W1 + (size_t)half * 128 * 128;  // rows half*128 ..

    for (int kc = 0; kc < 128; kc += BK) {
        // --- stage A tile [64][32]: 512 float4, 2 per thread ---
        #pragma unroll
        for (int i = 0; i < 2; ++i) {
            int l   = tid + i * 256;        // 0..511
            int row = l >> 3;               // 0..63
            int c4  = (l & 7) << 2;         // 0,4,..,28
            int gr  = m0 + row;
            if (gr >= n_nodes) gr = n_nodes - 1;   // clamp (stores guarded)
            float4 v = *(const float4*)(x + (size_t)gr * 128 + kc + c4);
            *(float4*)(&As[row * APAD + c4]) = v;
        }
        // --- stage B tile [32][128]: 1024 float4, 4 per thread ---
        #pragma unroll
        for (int i = 0; i < 4; ++i) {
            int l   = tid + i * 256;        // 0..1023
            int row = l >> 5;               // 0..31
            int c4  = (l & 31) << 2;        // 0..124
            float4 v = *(const float4*)(Wbase + (size_t)(kc + row) * 128 + c4);
            *(float4*)(&Bs[row * BN + c4]) = v;
        }
        __syncthreads();

        #pragma unroll 8
        for (int kk = 0; kk < BK; ++kk) {
            float a[8];
            #pragma unroll
            for (int i = 0; i < 8; ++i) a[i] = As[(tm * 8 + i) * APAD + kk];
            float4 b = *(const float4*)(&Bs[kk * BN + tn * 4]);
            #pragma unroll
            for (int i = 0; i < 8; ++i) {
                acc[i][0] = fmaf(a[i], b.x, acc[i][0]);
                acc[i][1] = fmaf(a[i], b.y, acc[i][1]);
                acc[i][2] = fmaf(a[i], b.z, acc[i][2]);
                acc[i][3] = fmaf(a[i], b.w, acc[i][3]);
            }
        }
        __syncthreads();
    }

    // --- store: P row-major [n_nodes][256] ---
    #pragma unroll
    for (int i = 0; i < 8; ++i) {
        int gr = m0 + tm * 8 + i;
        if (gr < n_nodes) {
            float4 v = make_float4(acc[i][0], acc[i][1], acc[i][2], acc[i][3]);
            *(float4*)(P + (size_t)gr * 256 + half * 128 + tn * 4) = v;
        }
    }
}

// ---------------------------------------------------------------------------
// Kernel 2: per edge, 16 lanes/edge.
// h = relu(P[src][0:128] + P[dst][128:256] + PetB[et]); logit = h.W2 + b2
// ---------------------------------------------------------------------------
__global__ __launch_bounds__(256) void edge_kernel(
    const int* __restrict__ ei, const int* __restrict__ et,
    const float* __restrict__ u, const float* __restrict__ P,
    const float* __restrict__ PetB, const float* __restrict__ W2,
    const float* __restrict__ b2, float* __restrict__ out, int E)
{
    int gtid = blockIdx.x * 256 + threadIdx.x;
    int e = gtid >> 4;
    int l = gtid & 15;
    if (e >= E) return;

    int src = ei[e];
    int dst = ei[E + e];
    int t   = et[e];
    float uu = u[e];

    const float4* ps = (const float4*)(P + (size_t)src * 256);
    const float4* pd = (const float4*)(P + (size_t)dst * 256 + 128);
    const float4* pe = (const float4*)(PetB + (size_t)t * 128);
    const float4* w2 = (const float4*)W2;

    float partial = 0.f;
    #pragma unroll
    for (int j = 0; j < 2; ++j) {
        int idx = l * 2 + j;                 // float4 index 0..31
        float4 a = ps[idx];
        float4 b = pd[idx];
        float4 c = pe[idx];
        float4 w = w2[idx];
        float h0 = fmaxf(a.x + b.x + c.x, 0.f);
        float h1 = fmaxf(a.y + b.y + c.y, 0.f);
        float h2 = fmaxf(a.z + b.z + c.z, 0.f);
        float h3 = fmaxf(a.w + b.w + c.w, 0.f);
        partial = fmaf(h0, w.x, partial);
        partial = fmaf(h1, w.y, partial);
        partial = fmaf(h2, w.z, partial);
        partial = fmaf(h3, w.w, partial);
    }
    // 16-lane tree reduce (groups are contiguous inside the wave64)
    partial += __shfl_xor(partial, 1);
    partial += __shfl_xor(partial, 2);
    partial += __shfl_xor(partial, 4);
    partial += __shfl_xor(partial, 8);

    if (l == 0) {
        float logit = partial + b2[0];
        float g  = logf(uu + EPS_G) - logf(1.f - uu + EPS_G);
        float z  = logit + g;                       // TEMP = 1.0
        float yv = 1.f / (1.f + expf(-z));
        float yh = yv > 0.5f ? 1.f : 0.f;
        float yst = (yh - yv) + yv;                 // match ref fp ordering
        out[e]         = logit;
        out[E + e]     = yv;
        out[2 * E + e] = yst;
    }
}

// ---------------------------------------------------------------------------
// Fallback (ws too small): wave(64) per edge, direct 272x128 MLP.
// ---------------------------------------------------------------------------
__global__ __launch_bounds__(256) void edge_direct_kernel(
    const float* __restrict__ x, const int* __restrict__ ei,
    const int* __restrict__ et, const float* __restrict__ u,
    const float* __restrict__ ee, const float* __restrict__ W1,
    const float* __restrict__ b1, const float* __restrict__ W2,
    const float* __restrict__ b2, float* __restrict__ out, int E)
{
    int wid  = (blockIdx.x * 256 + threadIdx.x) >> 6;
    int lane = threadIdx.x & 63;
    if (wid >= E) return;
    int src = ei[wid], dst = ei[E + wid], t = et[wid];
    int c0 = lane * 2;
    float acc0 = b1[c0], acc1 = b1[c0 + 1];
    for (int k = 0; k < 128; ++k) {
        float xs = x[(size_t)src * 128 + k];
        acc0 = fmaf(xs, W1[k * 128 + c0], acc0);
        acc1 = fmaf(xs, W1[k * 128 + c0 + 1], acc1);
    }
    for (int k = 0; k < 128; ++k) {
        float xd = x[(size_t)dst * 128 + k];
        acc0 = fmaf(xd, W1[(128 + k) * 128 + c0], acc0);
        acc1 = fmaf(xd, W1[(128 + k) * 128 + c0 + 1], acc1);
    }
    for (int k = 0; k < 16; ++k) {
        float ev = ee[t * 16 + k];
        acc0 = fmaf(ev, W1[(256 + k) * 128 + c0], acc0);
        acc1 = fmaf(ev, W1[(256 + k) * 128 + c0 + 1], acc1);
    }
    float partial = fmaxf(acc0, 0.f) * W2[c0] + fmaxf(acc1, 0.f) * W2[c0 + 1];
    #pragma unroll
    for (int off = 1; off < 64; off <<= 1) partial += __shfl_xor(partial, off);
    if (lane == 0) {
        float logit = partial + b2[0];
        float uu = u[wid];
        float g  = logf(uu + EPS_G) - logf(1.f - uu + EPS_G);
        float z  = logit + g;
        float yv = 1.f / (1.f + expf(-z));
        float yh = yv > 0.5f ? 1.f : 0.f;
        float yst = (yh - yv) + yv;
        out[wid]         = logit;
        out[E + wid]     = yv;
        out[2 * E + wid] = yst;
    }
}

// ---------------------------------------------------------------------------
extern "C" void kernel_launch(void* const* d_in, const int* in_sizes, int n_in,
                              void* d_out, int out_size, void* d_ws, size_t ws_size,
                              hipStream_t stream)
{
    const float* x   = (const float*)d_in[0];
    const int*   ei  = (const int*)d_in[1];
    const int*   et  = (const int*)d_in[2];
    const float* u   = (const float*)d_in[3];
    const float* ee  = (const float*)d_in[4];
    const float* W1  = (const float*)d_in[5];
    const float* b1  = (const float*)d_in[6];
    const float* W2  = (const float*)d_in[7];
    const float* b2  = (const float*)d_in[8];
    float* out = (float*)d_out;

    const int n_nodes  = in_sizes[0] / HIDDEN;       // 100000
    const int E        = in_sizes[2];                 // 1600000
    const int n_etypes = in_sizes[4] / 16;            // 512

    const size_t needP   = (size_t)n_nodes * 256 * sizeof(float);
    const size_t needPet = (size_t)n_etypes * 128 * sizeof(float);

    if (ws_size >= needP + needPet) {
        float* P    = (float*)d_ws;
        float* PetB = (float*)((char*)d_ws + needP);

        hipLaunchKernelGGL(etype_proj_kernel,
                           dim3((n_etypes * 128 + 255) / 256), dim3(256), 0, stream,
                           ee, W1, b1, PetB, n_etypes);
        hipLaunchKernelGGL(node_proj_kernel,
                           dim3((n_nodes + BM - 1) / BM, 2), dim3(256), 0, stream,
                           x, W1, P, n_nodes);
        hipLaunchKernelGGL(edge_kernel,
                           dim3(((size_t)E * 16 + 255) / 256), dim3(256), 0, stream,
                           ei, et, u, P, PetB, W2, b2, out, E);
    } else {
        hipLaunchKernelGGL(edge_direct_kernel,
                           dim3((E + 3) / 4), dim3(256), 0, stream,
                           x, ei, et, u, ee, W1, b1, W2, b2, out, E);
    }
}